// Round 13
// baseline (163.094 us; speedup 1.0000x reference)
//
#include <hip/hip_runtime.h>
#include <math.h>

#define NROWS 4096
#define SLEN  4096
#define RETN  4095   // number of log-returns
#define CHK   20     // floats per LDS chunk (16 data + 4 pad, keeps b128 aligned)

// -------------------------------------------------------------------------
// Kernel A: ep'[n][o] = emb @ cn_W1[512:576] + cn_b1   (16 x 128, b1 folded)
// -------------------------------------------------------------------------
__global__ __launch_bounds__(256) void k_ep(const float* __restrict__ emb,
                                            const float* __restrict__ cn_W1,
                                            const float* __restrict__ cn_b1,
                                            float* __restrict__ ep) {
    int idx = blockIdx.x * 256 + threadIdx.x;      // 2048 outputs, grid=8
    if (idx >= 16 * 128) return;
    int n = idx >> 7, o = idx & 127;
    float acc = cn_b1[o];
    const float* w = cn_W1 + 512 * 128;
    for (int i = 0; i < 64; ++i) acc = fmaf(emb[n * 64 + i], w[i * 128 + o], acc);
    ep[idx] = acc;
}

// -------------------------------------------------------------------------
// Kernel 1 v4b: per-row price stats. (256,4) bound kills the 1-dword/thread
// scratch spill seen in round 9 (VGPR was 64 exactly; cap is now 128).
// -------------------------------------------------------------------------
__global__ __launch_bounds__(256, 4) void k_stats(const float* __restrict__ price,
                                                  float* __restrict__ combined,
                                                  float* __restrict__ volin) {
    __shared__ float scm[260 * CHK];   // 20.8 KB: prices, then log2-returns
    __shared__ float red[6][4];

    const int tid = threadIdx.x;
    const int row = blockIdx.x;
    const float* pr = price + (size_t)row * SLEN;

    float pA = 0.f, pB = 0.f;
    if (tid == 0) { pA = pr[SLEN - 10]; pB = pr[SLEN - 1]; }

    if (tid < 40) { scm[tid] = 0.f; scm[258 * CHK + tid] = 0.f; }

    #pragma unroll
    for (int it = 0; it < 4; ++it) {
        const int i = it * 256 + tid;                  // float4 index
        const float4 v = ((const float4*)pr)[i];
        *(float4*)&scm[(2 + (i >> 2)) * CHK + ((4 * i) & 15)] = v;
    }
    __syncthreads();

    const int s0 = tid * 16;

    float hb[20], x_[16];
    *(float4*)&hb[0] = *(const float4*)&scm[tid * CHK + 12];
    #pragma unroll
    for (int k = 0; k < 4; ++k)
        *(float4*)&hb[4 + 4 * k] = *(const float4*)&scm[(tid + 1) * CHK + 4 * k];
    #pragma unroll
    for (int k = 0; k < 4; ++k)
        *(float4*)&x_[4 * k] = *(const float4*)&scm[(tid + 2) * CHK + 4 * k];
    const float pn = scm[(tid + 3) * CHK];

    float W = 0.f;
    #pragma unroll
    for (int k = 0; k < 20; ++k) W += hb[k];
    float st = 0.f, s1p = 0.f, s2p = 0.f;
    #pragma unroll
    for (int d = 0; d < 16; ++d) {
        const float x = x_[d];
        W += x - hb[d];
        float inv_cnt = 0.05f;
        if (s0 == 0)                 inv_cnt = 1.0f / (float)(d + 1);
        else if (s0 == 16 && d < 3)  inv_cnt = 1.0f / (float)(17 + d);
        const float sma = W * inv_cnt;
        st  = fmaf(x - sma, __builtin_amdgcn_rcpf(sma + 1e-8f), st);
        s1p += x;
        s2p = fmaf(x, x, s2p);
    }

    float lg[17];
    #pragma unroll
    for (int d = 0; d < 16; ++d) lg[d] = __builtin_amdgcn_logf(fmaxf(x_[d], 1e-8f));
    lg[16] = __builtin_amdgcn_logf(fmaxf(pn, 1e-8f));
    float rs[36];
    #pragma unroll
    for (int d = 0; d < 16; ++d) rs[d] = lg[d + 1] - lg[d];

    __syncthreads();
    #pragma unroll
    for (int k = 0; k < 4; ++k)
        *(float4*)&scm[(tid + 2) * CHK + 4 * k] = *(const float4*)&rs[4 * k];
    __syncthreads();

    #pragma unroll
    for (int k = 0; k < 4; ++k)
        *(float4*)&rs[16 + 4 * k] = *(const float4*)&scm[(tid + 3) * CHK + 4 * k];
    *(float4*)&rs[32] = *(const float4*)&scm[(tid + 4) * CHK];

    float S5 = 0.f, Q5 = 0.f, S10 = 0.f, Q10 = 0.f, S20 = 0.f, Q20 = 0.f;
    #pragma unroll
    for (int j = 0; j < 20; ++j) {
        const float x = rs[j];
        S20 += x; Q20 = fmaf(x, x, Q20);
        if (j < 10) { S10 += x; Q10 = fmaf(x, x, Q10); }
        if (j < 5)  { S5  += x; Q5  = fmaf(x, x, Q5); }
    }

    #define SQT(S, Q, invw) \
        __builtin_amdgcn_sqrtf(fmaxf(fmaf(-(S) * (invw), (S), (Q)), 0.f))

    float v5 = 0.f, v10 = 0.f, v20 = 0.f;
    if (tid < 254) {
        #pragma unroll
        for (int d = 0; d < 16; ++d) {
            v5  += SQT(S5,  Q5,  0.2f);
            v10 += SQT(S10, Q10, 0.1f);
            v20 += SQT(S20, Q20, 0.05f);
            const float xo = rs[d], qo = xo * xo;
            const float a5 = rs[d + 5], a10 = rs[d + 10], a20 = rs[d + 20];
            S5  += a5  - xo;  Q5  = fmaf(a5,  a5,  Q5)  - qo;
            S10 += a10 - xo;  Q10 = fmaf(a10, a10, Q10) - qo;
            S20 += a20 - xo;  Q20 = fmaf(a20, a20, Q20) - qo;
        }
    } else {
        #pragma unroll
        for (int d = 0; d < 16; ++d) {
            const int i = s0 + d;
            if (i < 4091) v5  += SQT(S5,  Q5,  0.2f);
            if (i < 4086) v10 += SQT(S10, Q10, 0.1f);
            if (i < 4076) v20 += SQT(S20, Q20, 0.05f);
            const float xo = rs[d], qo = xo * xo;
            const float a5 = rs[d + 5], a10 = rs[d + 10], a20 = rs[d + 20];
            S5  += a5  - xo;  Q5  = fmaf(a5,  a5,  Q5)  - qo;
            S10 += a10 - xo;  Q10 = fmaf(a10, a10, Q10) - qo;
            S20 += a20 - xo;  Q20 = fmaf(a20, a20, Q20) - qo;
        }
    }
    #undef SQT

    {
        float vals[6] = {s1p, s2p, st, v5, v10, v20};
        const int lane = tid & 63, wid = tid >> 6;
        #pragma unroll
        for (int v = 0; v < 6; ++v) {
            float x = vals[v];
            for (int o = 32; o > 0; o >>= 1) x += __shfl_xor(x, o, 64);
            if (lane == 0) red[v][wid] = x;
        }
    }
    __syncthreads();
    if (tid == 0) {
        const float sum_p  = red[0][0] + red[0][1] + red[0][2] + red[0][3];
        const float sum_p2 = red[1][0] + red[1][1] + red[1][2] + red[1][3];
        const float sum_t  = red[2][0] + red[2][1] + red[2][2] + red[2][3];
        const float sv5    = red[3][0] + red[3][1] + red[3][2] + red[3][3];
        const float sv10   = red[4][0] + red[4][1] + red[4][2] + red[4][3];
        const float sv20   = red[5][0] + red[5][1] + red[5][2] + red[5][3];
        const float pmean = sum_p * (1.f / 4096.f);
        const float varp  = fmaf(-sum_p * (1.f / 4096.f), sum_p, sum_p2) * (1.f / 4095.f);
        const float pstd  = __builtin_amdgcn_sqrtf(fmaxf(varp, 0.f));
        const float ipm   = __builtin_amdgcn_rcpf(pmean + 1e-8f);
        combined[row * 4 + 0] = sum_t * (1.f / 4096.f);
        combined[row * 4 + 1] = (pB - pA) * __builtin_amdgcn_rcpf(pA + 1e-8f);
        combined[row * 4 + 2] = (pB - pmean) * ipm;
        combined[row * 4 + 3] = pstd * ipm;
        const float LN2 = 0.6931471805599453f;
        volin[row * 3 + 0] = sv5  * (LN2 * 0.5f                 / 4091.f);
        volin[row * 3 + 1] = sv10 * (LN2 * (1.f / 3.f)          / 4086.f);
        volin[row * 3 + 2] = sv20 * (LN2 * 0.22941573387056174f / 4076.f);
    }
}

// -------------------------------------------------------------------------
// Kernel 2+3 FUSED v3 (k_mc): 4 rows/block, 256 threads, grid 1024.
// LDS ~51.5 KB -> 3 blocks/CU = 12 waves/CU (round-10 was 79 KB -> 8 waves).
// ep' lives in registers until cross-A's partials (uni) are consumed, then
// is written into uni (round-4 pattern). Phases are 4-row versions of the
// round-10 code. launch_bounds(256,3): VGPR cap 170 >> ~90 live (no spill).
// -------------------------------------------------------------------------
__global__ __launch_bounds__(256, 3) void k_mc(const float* __restrict__ combined,
                                               const float* __restrict__ volin,
                                               const float* __restrict__ re_W,  const float* __restrict__ re_b,
                                               const float* __restrict__ re_g,  const float* __restrict__ re_be,
                                               const float* __restrict__ rh_W1, const float* __restrict__ rh_b1,
                                               const float* __restrict__ rh_W2, const float* __restrict__ rh_b2,
                                               const float* __restrict__ rv_W,  const float* __restrict__ rv_b,
                                               const float* __restrict__ rv_g,  const float* __restrict__ rv_be,
                                               const float* __restrict__ vs_W,  const float* __restrict__ vs_b,
                                               const float* __restrict__ vs_g,  const float* __restrict__ vs_be,
                                               const float* __restrict__ vc_W1, const float* __restrict__ vc_b1,
                                               const float* __restrict__ vc_W2, const float* __restrict__ vc_b2,
                                               const float* __restrict__ cn_W1,
                                               const float* __restrict__ cn_W2,
                                               const float* __restrict__ cn_b2,
                                               const float* __restrict__ cn_W3,
                                               const float* __restrict__ cn_b3,
                                               const float* __restrict__ ep,
                                               float* __restrict__ out_rf, float* __restrict__ out_rp,
                                               float* __restrict__ out_vf, float* __restrict__ out_vr,
                                               float* __restrict__ scores) {
    __shared__ __align__(16) float w2s[128 * 64];   // 32 KB  [c][j]
    __shared__ __align__(16) float uni[2112];       // 8.25 KB: psx[4][4][128], then epb[16][132]
    __shared__ __align__(16) float rf_lds[4][256];  // 4 KB
    __shared__ __align__(16) float vf_lds[4][256];  // 4 KB
    __shared__ __align__(16) float mvp_s[4][128];   // 2 KB (broadcast reads only)
    __shared__ float hid_s[4][64];
    __shared__ float prt[4][4];
    __shared__ float cmb_s[4][4];
    __shared__ float vol_s[4][3];

    const int tid  = threadIdx.x;
    const int lane = tid & 63;
    const int wid  = tid >> 6;            // 0..3
    const int row0 = blockIdx.x * 4;

    // preload ep' (b1 folded): 8 floats/thread, consumed after cross-A
    const float4 ep0 = ((const float4*)ep)[2 * tid];
    const float4 ep1 = ((const float4*)ep)[2 * tid + 1];

    // ---- stage W2 (8 float4/thread), row inputs ----
    #pragma unroll
    for (int k = 0; k < 8; ++k) {
        const int idx = k * 256 + tid;              // float4 index 0..2047
        *(float4*)&w2s[4 * idx] = *(const float4*)(cn_W2 + 4 * idx);
    }
    if (tid < 16) cmb_s[tid >> 2][tid & 3] = combined[(size_t)(row0 + (tid >> 2)) * 4 + (tid & 3)];
    else if (tid < 28) { int t = tid - 16; vol_s[t / 3][t % 3] = volin[(size_t)(row0 + t / 3) * 3 + t % 3]; }
    __syncthreads();

    // ================= MLP PHASES =================
    // ---- Phase A: regime expert (k=wid), rows 0..3, LN over o=lane ----
    {
        const float* w = re_W + wid * 256;
        const float w0 = w[lane], w1 = w[64 + lane], w2 = w[128 + lane], w3 = w[192 + lane];
        const float b  = re_b[wid * 64 + lane];
        const float gg = re_g[wid * 64 + lane], bb = re_be[wid * 64 + lane];
        float h[4], sm[4], sq[4];
        #pragma unroll
        for (int r = 0; r < 4; ++r) {
            float v = fmaf(cmb_s[r][0], w0, fmaf(cmb_s[r][1], w1,
                      fmaf(cmb_s[r][2], w2, fmaf(cmb_s[r][3], w3, b))));
            h[r] = fmaxf(v, 0.f);
            sm[r] = h[r]; sq[r] = h[r] * h[r];
        }
        #pragma unroll
        for (int off = 32; off > 0; off >>= 1) {
            #pragma unroll
            for (int r = 0; r < 4; ++r) {
                sm[r] += __shfl_xor(sm[r], off, 64);
                sq[r] += __shfl_xor(sq[r], off, 64);
            }
        }
        #pragma unroll
        for (int r = 0; r < 4; ++r) {
            const float mu  = sm[r] * (1.f / 64.f);
            const float var = fmaxf(sq[r] * (1.f / 64.f) - mu * mu, 0.f);
            const float y = (h[r] - mu) * rsqrtf(var + 1e-5f) * gg + bb;
            rf_lds[r][wid * 64 + lane] = y;
            out_rf[(size_t)(row0 + r) * 256 + wid * 64 + lane] = y;
        }
    }
    __syncthreads();

    // ---- Phase B: rh hidden partials, i-split (i0 = 64*wid), rows 0..3 ----
    {
        const int i0 = wid * 64;
        float acc[4] = {0.f, 0.f, 0.f, 0.f};
        for (int i = 0; i < 64; ++i) {
            const float wv = rh_W1[(size_t)(i0 + i) * 64 + lane];
            #pragma unroll
            for (int r = 0; r < 4; ++r) acc[r] = fmaf(rf_lds[r][i0 + i], wv, acc[r]);
        }
        #pragma unroll
        for (int r = 0; r < 4; ++r) uni[wid * 512 + r * 128 + lane] = acc[r];
    }
    __syncthreads();

    // ---- Phase C: combine -> hid (4x64), 1 output/thread ----
    {
        const int r = tid >> 6, o = tid & 63;
        const float v = uni[r * 128 + o] + uni[512 + r * 128 + o]
                      + uni[1024 + r * 128 + o] + uni[1536 + r * 128 + o] + rh_b1[o];
        hid_s[r][o] = fmaxf(v, 0.f);
    }
    __syncthreads();

    // ---- Phase D: regime logits + softmax (16 threads) ----
    if (tid < 16) {
        const int r = tid >> 2, j = tid & 3;
        float acc = rh_b2[j];
        for (int i = 0; i < 64; ++i) acc = fmaf(hid_s[r][i], rh_W2[i * 4 + j], acc);
        float m = acc;
        m = fmaxf(m, __shfl_xor(m, 1, 64));
        m = fmaxf(m, __shfl_xor(m, 2, 64));
        const float e = expf(acc - m);
        float s = e;
        s += __shfl_xor(s, 1, 64);
        s += __shfl_xor(s, 2, 64);
        out_rp[(size_t)(row0 + r) * 4 + j] = e / s;
    }

    // ---- Phase E: rv + LN/128 (g = tid>>7 handles rows 2g, 2g+1) ----
    {
        const int o = tid & 127, g = tid >> 7;
        const float w0 = rv_W[o], w1 = rv_W[128 + o], w2 = rv_W[256 + o];
        const float b = rv_b[o], gg = rv_g[o], bb = rv_be[o];
        float h[2], sm[2], sq[2];
        #pragma unroll
        for (int r2 = 0; r2 < 2; ++r2) {
            const int r = g * 2 + r2;
            float v = fmaf(vol_s[r][0], w0, fmaf(vol_s[r][1], w1, fmaf(vol_s[r][2], w2, b)));
            h[r2] = fmaxf(v, 0.f);
            sm[r2] = h[r2]; sq[r2] = h[r2] * h[r2];
        }
        #pragma unroll
        for (int off = 32; off > 0; off >>= 1) {
            #pragma unroll
            for (int r2 = 0; r2 < 2; ++r2) {
                sm[r2] += __shfl_xor(sm[r2], off, 64);
                sq[r2] += __shfl_xor(sq[r2], off, 64);
            }
        }
        if (lane == 0) {
            #pragma unroll
            for (int r2 = 0; r2 < 2; ++r2) { prt[wid][r2 * 2] = sm[r2]; prt[wid][r2 * 2 + 1] = sq[r2]; }
        }
        __syncthreads();
        #pragma unroll
        for (int r2 = 0; r2 < 2; ++r2) {
            const float S = prt[2 * g][2 * r2]     + prt[2 * g + 1][2 * r2];
            const float Q = prt[2 * g][2 * r2 + 1] + prt[2 * g + 1][2 * r2 + 1];
            const float mu  = S * (1.f / 128.f);
            const float var = fmaxf(Q * (1.f / 128.f) - mu * mu, 0.f);
            const float y = (h[r2] - mu) * rsqrtf(var + 1e-5f) * gg + bb;
            vf_lds[g * 2 + r2][o] = y;
            out_vf[(size_t)(row0 + g * 2 + r2) * 256 + o] = y;
        }
    }
    __syncthreads();

    // ---- Phase F: vs = LN(relu(rv @ vs_W + b)) ----
    {
        const int o = tid & 127, g = tid >> 7;
        float acc[2];
        const float b = vs_b[o];
        acc[0] = b; acc[1] = b;
        for (int i = 0; i < 128; ++i) {
            const float wv = vs_W[(size_t)i * 128 + o];
            #pragma unroll
            for (int r2 = 0; r2 < 2; ++r2) acc[r2] = fmaf(vf_lds[g * 2 + r2][i], wv, acc[r2]);
        }
        const float gg = vs_g[o], bb = vs_be[o];
        float h[2], sm[2], sq[2];
        #pragma unroll
        for (int r2 = 0; r2 < 2; ++r2) {
            h[r2] = fmaxf(acc[r2], 0.f);
            sm[r2] = h[r2]; sq[r2] = h[r2] * h[r2];
        }
        #pragma unroll
        for (int off = 32; off > 0; off >>= 1) {
            #pragma unroll
            for (int r2 = 0; r2 < 2; ++r2) {
                sm[r2] += __shfl_xor(sm[r2], off, 64);
                sq[r2] += __shfl_xor(sq[r2], off, 64);
            }
        }
        __syncthreads();   // prt from E fully consumed
        if (lane == 0) {
            #pragma unroll
            for (int r2 = 0; r2 < 2; ++r2) { prt[wid][r2 * 2] = sm[r2]; prt[wid][r2 * 2 + 1] = sq[r2]; }
        }
        __syncthreads();
        #pragma unroll
        for (int r2 = 0; r2 < 2; ++r2) {
            const float S = prt[2 * g][2 * r2]     + prt[2 * g + 1][2 * r2];
            const float Q = prt[2 * g][2 * r2 + 1] + prt[2 * g + 1][2 * r2 + 1];
            const float mu  = S * (1.f / 128.f);
            const float var = fmaxf(Q * (1.f / 128.f) - mu * mu, 0.f);
            const float y = (h[r2] - mu) * rsqrtf(var + 1e-5f) * gg + bb;
            vf_lds[g * 2 + r2][128 + o] = y;
            out_vf[(size_t)(row0 + g * 2 + r2) * 256 + 128 + o] = y;
        }
    }
    __syncthreads();

    // ---- Phase G: vc hidden partials ----
    {
        const int i0 = wid * 64;
        float acc[4] = {0.f, 0.f, 0.f, 0.f};
        for (int i = 0; i < 64; ++i) {
            const float wv = vc_W1[(size_t)(i0 + i) * 64 + lane];
            #pragma unroll
            for (int r = 0; r < 4; ++r) acc[r] = fmaf(vf_lds[r][i0 + i], wv, acc[r]);
        }
        #pragma unroll
        for (int r = 0; r < 4; ++r) uni[wid * 512 + r * 128 + lane] = acc[r];
    }
    __syncthreads();

    // ---- Phase H: combine -> hid, logits, softmax ----
    {
        const int r = tid >> 6, o = tid & 63;
        const float v = uni[r * 128 + o] + uni[512 + r * 128 + o]
                      + uni[1024 + r * 128 + o] + uni[1536 + r * 128 + o] + vc_b1[o];
        hid_s[r][o] = fmaxf(v, 0.f);
    }
    __syncthreads();
    if (tid < 16) {
        const int r = tid >> 2, j = tid & 3;
        float acc = vc_b2[j];
        for (int i = 0; i < 64; ++i) acc = fmaf(hid_s[r][i], vc_W2[i * 4 + j], acc);
        float m = acc;
        m = fmaxf(m, __shfl_xor(m, 1, 64));
        m = fmaxf(m, __shfl_xor(m, 2, 64));
        const float e = expf(acc - m);
        float s = e;
        s += __shfl_xor(s, 1, 64);
        s += __shfl_xor(s, 2, 64);
        out_vr[(size_t)(row0 + r) * 4 + j] = e / s;
    }
    __syncthreads();   // uni free; rf/vf final

    // ================= CROSS PHASES =================
    // ---- phase A: wave wid covers i in [128*wid, +128), rows 0..3 ----
    // lane = 32p + q: p = i parity, o = 4q..4q+3
    {
        const int p = lane >> 5;
        const int q = lane & 31;
        const float* mbase = (wid < 2) ? &rf_lds[0][0] + wid * 128
                                       : &vf_lds[0][0] + (wid - 2) * 128;
        float acc[4][4] = {{0.f}};
        #pragma unroll 8
        for (int s = 0; s < 64; ++s) {
            const int i = 2 * s + p;
            const float4 w1v = *(const float4*)(cn_W1 + (size_t)(wid * 128 + i) * 128 + 4 * q);
            #pragma unroll
            for (int r = 0; r < 4; ++r) {
                const float m = mbase[r * 256 + i];
                acc[r][0] = fmaf(m, w1v.x, acc[r][0]);
                acc[r][1] = fmaf(m, w1v.y, acc[r][1]);
                acc[r][2] = fmaf(m, w1v.z, acc[r][2]);
                acc[r][3] = fmaf(m, w1v.w, acc[r][3]);
            }
        }
        #pragma unroll
        for (int r = 0; r < 4; ++r) {
            #pragma unroll
            for (int k = 0; k < 4; ++k) acc[r][k] += __shfl_xor(acc[r][k], 32, 64);
        }
        if (p == 0) {
            #pragma unroll
            for (int r = 0; r < 4; ++r)
                *(float4*)&uni[wid * 512 + r * 128 + 4 * q] =
                    make_float4(acc[r][0], acc[r][1], acc[r][2], acc[r][3]);
        }
    }
    __syncthreads();

    // combine 4 wave-partials -> mvp_s[4][128] (2 outputs/thread)
    #pragma unroll
    for (int k = 0; k < 2; ++k) {
        const int idx = k * 256 + tid;
        const int r = idx >> 7, c = idx & 127;
        mvp_s[r][c] = uni[r * 128 + c] + uni[512 + r * 128 + c]
                    + uni[1024 + r * 128 + c] + uni[1536 + r * 128 + c];
    }
    __syncthreads();   // uni fully consumed

    // ---- write ep' into uni as epb[16][132] ----
    {
        const int ns = tid >> 4, c = (tid * 8) & 127;
        *(float4*)&uni[ns * 132 + c]     = ep0;
        *(float4*)&uni[ns * 132 + c + 4] = ep1;
    }
    __syncthreads();

    // ---- phase B: thread = (ns = tid>>4, t = tid&15), j = 4t..4t+3, 4 rows ----
    {
        const int ns = tid >> 4;
        const int t  = tid & 15;
        float acc[4][4];
        #pragma unroll
        for (int r = 0; r < 4; ++r)
            #pragma unroll
            for (int k = 0; k < 4; ++k) acc[r][k] = 0.f;

        #pragma unroll 2
        for (int c = 0; c < 128; c += 4) {
            float4 m4[4];
            #pragma unroll
            for (int r = 0; r < 4; ++r) m4[r] = *(const float4*)&mvp_s[r][c];
            const float4 e4 = *(const float4*)&uni[ns * 132 + c];
            {   const float4 w2v = *(const float4*)&w2s[(c + 0) * 64 + 4 * t];
                #pragma unroll
                for (int r = 0; r < 4; ++r) {
                    const float h = fmaxf(m4[r].x + e4.x, 0.f);
                    acc[r][0] = fmaf(h, w2v.x, acc[r][0]); acc[r][1] = fmaf(h, w2v.y, acc[r][1]);
                    acc[r][2] = fmaf(h, w2v.z, acc[r][2]); acc[r][3] = fmaf(h, w2v.w, acc[r][3]); } }
            {   const float4 w2v = *(const float4*)&w2s[(c + 1) * 64 + 4 * t];
                #pragma unroll
                for (int r = 0; r < 4; ++r) {
                    const float h = fmaxf(m4[r].y + e4.y, 0.f);
                    acc[r][0] = fmaf(h, w2v.x, acc[r][0]); acc[r][1] = fmaf(h, w2v.y, acc[r][1]);
                    acc[r][2] = fmaf(h, w2v.z, acc[r][2]); acc[r][3] = fmaf(h, w2v.w, acc[r][3]); } }
            {   const float4 w2v = *(const float4*)&w2s[(c + 2) * 64 + 4 * t];
                #pragma unroll
                for (int r = 0; r < 4; ++r) {
                    const float h = fmaxf(m4[r].z + e4.z, 0.f);
                    acc[r][0] = fmaf(h, w2v.x, acc[r][0]); acc[r][1] = fmaf(h, w2v.y, acc[r][1]);
                    acc[r][2] = fmaf(h, w2v.z, acc[r][2]); acc[r][3] = fmaf(h, w2v.w, acc[r][3]); } }
            {   const float4 w2v = *(const float4*)&w2s[(c + 3) * 64 + 4 * t];
                #pragma unroll
                for (int r = 0; r < 4; ++r) {
                    const float h = fmaxf(m4[r].w + e4.w, 0.f);
                    acc[r][0] = fmaf(h, w2v.x, acc[r][0]); acc[r][1] = fmaf(h, w2v.y, acc[r][1]);
                    acc[r][2] = fmaf(h, w2v.z, acc[r][2]); acc[r][3] = fmaf(h, w2v.w, acc[r][3]); } }
        }

        const float4 b2v = *(const float4*)(cn_b2 + 4 * t);
        const float4 w3v = *(const float4*)(cn_W3 + 4 * t);
        const float  b3v = cn_b3[0];
        #pragma unroll
        for (int r = 0; r < 4; ++r) {
            float s =      fmaxf(acc[r][0] + b2v.x, 0.f) * w3v.x;
            s = fmaf(fmaxf(acc[r][1] + b2v.y, 0.f), w3v.y, s);
            s = fmaf(fmaxf(acc[r][2] + b2v.z, 0.f), w3v.z, s);
            s = fmaf(fmaxf(acc[r][3] + b2v.w, 0.f), w3v.w, s);
            s += __shfl_xor(s, 1, 64);
            s += __shfl_xor(s, 2, 64);
            s += __shfl_xor(s, 4, 64);
            s += __shfl_xor(s, 8, 64);
            if (t == 0) scores[(size_t)(row0 + r) * 16 + ns] = s + b3v;
        }
    }
}

// -------------------------------------------------------------------------
extern "C" void kernel_launch(void* const* d_in, const int* in_sizes, int n_in,
                              void* d_out, int out_size, void* d_ws, size_t ws_size,
                              hipStream_t stream) {
    (void)in_sizes; (void)n_in; (void)out_size; (void)ws_size;

    const float* price = (const float*)d_in[0];
    const float* re_W  = (const float*)d_in[1];
    const float* re_b  = (const float*)d_in[2];
    const float* re_g  = (const float*)d_in[3];
    const float* re_be = (const float*)d_in[4];
    const float* rh_W1 = (const float*)d_in[5];
    const float* rh_b1 = (const float*)d_in[6];
    const float* rh_W2 = (const float*)d_in[7];
    const float* rh_b2 = (const float*)d_in[8];
    const float* rv_W  = (const float*)d_in[9];
    const float* rv_b  = (const float*)d_in[10];
    const float* rv_g  = (const float*)d_in[11];
    const float* rv_be = (const float*)d_in[12];
    const float* vs_W  = (const float*)d_in[13];
    const float* vs_b  = (const float*)d_in[14];
    const float* vs_g  = (const float*)d_in[15];
    const float* vs_be = (const float*)d_in[16];
    const float* vc_W1 = (const float*)d_in[17];
    const float* vc_b1 = (const float*)d_in[18];
    const float* vc_W2 = (const float*)d_in[19];
    const float* vc_b2 = (const float*)d_in[20];
    const float* emb   = (const float*)d_in[21];
    const float* cn_W1 = (const float*)d_in[22];
    const float* cn_b1 = (const float*)d_in[23];
    const float* cn_W2 = (const float*)d_in[24];
    const float* cn_b2 = (const float*)d_in[25];
    const float* cn_W3 = (const float*)d_in[26];
    const float* cn_b3 = (const float*)d_in[27];

    float* out    = (float*)d_out;
    float* out_rf = out;                       // 4096*256
    float* out_rp = out_rf + 4096 * 256;       // 4096*4
    float* out_vf = out_rp + 4096 * 4;         // 4096*256
    float* out_vr = out_vf + 4096 * 256;       // 4096*4
    float* out_sc = out_vr + 4096 * 4;         // 4096*16

    float* ws       = (float*)d_ws;
    float* combined = ws;                      // 4096*4
    float* volin    = combined + 4096 * 4;     // 4096*3
    float* ep       = volin + 4096 * 3;        // 16*128

    hipLaunchKernelGGL(k_ep,    dim3(8),    dim3(256), 0, stream, emb, cn_W1, cn_b1, ep);
    hipLaunchKernelGGL(k_stats, dim3(4096), dim3(256), 0, stream, price, combined, volin);
    hipLaunchKernelGGL(k_mc,    dim3(1024), dim3(256), 0, stream, combined, volin,
                       re_W, re_b, re_g, re_be, rh_W1, rh_b1, rh_W2, rh_b2,
                       rv_W, rv_b, rv_g, rv_be, vs_W, vs_b, vs_g, vs_be,
                       vc_W1, vc_b1, vc_W2, vc_b2,
                       cn_W1, cn_W2, cn_b2, cn_W3, cn_b3, ep,
                       out_rf, out_rp, out_vf, out_vr, out_sc);
}

// Round 14
// 97.546 us; speedup vs baseline: 1.6720x; 1.6720x over previous
//
#include <hip/hip_runtime.h>
#include <math.h>

#define NROWS 4096
#define SLEN  4096
#define RETN  4095   // number of log-returns
#define CHK   20     // floats per LDS chunk (16 data + 4 pad, keeps b128 aligned)

// -------------------------------------------------------------------------
// Kernel A: ep'[n][o] = emb @ cn_W1[512:576] + cn_b1   (16 x 128, b1 folded)
// -------------------------------------------------------------------------
__global__ __launch_bounds__(256) void k_ep(const float* __restrict__ emb,
                                            const float* __restrict__ cn_W1,
                                            const float* __restrict__ cn_b1,
                                            float* __restrict__ ep) {
    int idx = blockIdx.x * 256 + threadIdx.x;      // 2048 outputs, grid=8
    if (idx >= 16 * 128) return;
    int n = idx >> 7, o = idx & 127;
    float acc = cn_b1[o];
    const float* w = cn_W1 + 512 * 128;
    for (int i = 0; i < 64; ++i) acc = fmaf(emb[n * 64 + i], w[i * 128 + o], acc);
    ep[idx] = acc;
}

// -------------------------------------------------------------------------
// Kernel 1 v4 (round-9/10 verbatim): per-row price stats.
// -------------------------------------------------------------------------
__global__ void k_stats(const float* __restrict__ price,
                        float* __restrict__ combined,
                        float* __restrict__ volin) {
    __shared__ float scm[260 * CHK];   // 20.8 KB: prices, then log2-returns
    __shared__ float red[6][4];

    const int tid = threadIdx.x;
    const int row = blockIdx.x;
    const float* pr = price + (size_t)row * SLEN;

    float pA = 0.f, pB = 0.f;
    if (tid == 0) { pA = pr[SLEN - 10]; pB = pr[SLEN - 1]; }

    if (tid < 40) { scm[tid] = 0.f; scm[258 * CHK + tid] = 0.f; }

    #pragma unroll
    for (int it = 0; it < 4; ++it) {
        const int i = it * 256 + tid;                  // float4 index
        const float4 v = ((const float4*)pr)[i];
        *(float4*)&scm[(2 + (i >> 2)) * CHK + ((4 * i) & 15)] = v;
    }
    __syncthreads();

    const int s0 = tid * 16;

    float hb[20], x_[16];
    *(float4*)&hb[0] = *(const float4*)&scm[tid * CHK + 12];
    #pragma unroll
    for (int k = 0; k < 4; ++k)
        *(float4*)&hb[4 + 4 * k] = *(const float4*)&scm[(tid + 1) * CHK + 4 * k];
    #pragma unroll
    for (int k = 0; k < 4; ++k)
        *(float4*)&x_[4 * k] = *(const float4*)&scm[(tid + 2) * CHK + 4 * k];
    const float pn = scm[(tid + 3) * CHK];

    float W = 0.f;
    #pragma unroll
    for (int k = 0; k < 20; ++k) W += hb[k];
    float st = 0.f, s1p = 0.f, s2p = 0.f;
    #pragma unroll
    for (int d = 0; d < 16; ++d) {
        const float x = x_[d];
        W += x - hb[d];
        float inv_cnt = 0.05f;
        if (s0 == 0)                 inv_cnt = 1.0f / (float)(d + 1);
        else if (s0 == 16 && d < 3)  inv_cnt = 1.0f / (float)(17 + d);
        const float sma = W * inv_cnt;
        st  = fmaf(x - sma, __builtin_amdgcn_rcpf(sma + 1e-8f), st);
        s1p += x;
        s2p = fmaf(x, x, s2p);
    }

    float lg[17];
    #pragma unroll
    for (int d = 0; d < 16; ++d) lg[d] = __builtin_amdgcn_logf(fmaxf(x_[d], 1e-8f));
    lg[16] = __builtin_amdgcn_logf(fmaxf(pn, 1e-8f));
    float rs[36];
    #pragma unroll
    for (int d = 0; d < 16; ++d) rs[d] = lg[d + 1] - lg[d];

    __syncthreads();
    #pragma unroll
    for (int k = 0; k < 4; ++k)
        *(float4*)&scm[(tid + 2) * CHK + 4 * k] = *(const float4*)&rs[4 * k];
    __syncthreads();

    #pragma unroll
    for (int k = 0; k < 4; ++k)
        *(float4*)&rs[16 + 4 * k] = *(const float4*)&scm[(tid + 3) * CHK + 4 * k];
    *(float4*)&rs[32] = *(const float4*)&scm[(tid + 4) * CHK];

    float S5 = 0.f, Q5 = 0.f, S10 = 0.f, Q10 = 0.f, S20 = 0.f, Q20 = 0.f;
    #pragma unroll
    for (int j = 0; j < 20; ++j) {
        const float x = rs[j];
        S20 += x; Q20 = fmaf(x, x, Q20);
        if (j < 10) { S10 += x; Q10 = fmaf(x, x, Q10); }
        if (j < 5)  { S5  += x; Q5  = fmaf(x, x, Q5); }
    }

    #define SQT(S, Q, invw) \
        __builtin_amdgcn_sqrtf(fmaxf(fmaf(-(S) * (invw), (S), (Q)), 0.f))

    float v5 = 0.f, v10 = 0.f, v20 = 0.f;
    if (tid < 254) {
        #pragma unroll
        for (int d = 0; d < 16; ++d) {
            v5  += SQT(S5,  Q5,  0.2f);
            v10 += SQT(S10, Q10, 0.1f);
            v20 += SQT(S20, Q20, 0.05f);
            const float xo = rs[d], qo = xo * xo;
            const float a5 = rs[d + 5], a10 = rs[d + 10], a20 = rs[d + 20];
            S5  += a5  - xo;  Q5  = fmaf(a5,  a5,  Q5)  - qo;
            S10 += a10 - xo;  Q10 = fmaf(a10, a10, Q10) - qo;
            S20 += a20 - xo;  Q20 = fmaf(a20, a20, Q20) - qo;
        }
    } else {
        #pragma unroll
        for (int d = 0; d < 16; ++d) {
            const int i = s0 + d;
            if (i < 4091) v5  += SQT(S5,  Q5,  0.2f);
            if (i < 4086) v10 += SQT(S10, Q10, 0.1f);
            if (i < 4076) v20 += SQT(S20, Q20, 0.05f);
            const float xo = rs[d], qo = xo * xo;
            const float a5 = rs[d + 5], a10 = rs[d + 10], a20 = rs[d + 20];
            S5  += a5  - xo;  Q5  = fmaf(a5,  a5,  Q5)  - qo;
            S10 += a10 - xo;  Q10 = fmaf(a10, a10, Q10) - qo;
            S20 += a20 - xo;  Q20 = fmaf(a20, a20, Q20) - qo;
        }
    }
    #undef SQT

    {
        float vals[6] = {s1p, s2p, st, v5, v10, v20};
        const int lane = tid & 63, wid = tid >> 6;
        #pragma unroll
        for (int v = 0; v < 6; ++v) {
            float x = vals[v];
            for (int o = 32; o > 0; o >>= 1) x += __shfl_xor(x, o, 64);
            if (lane == 0) red[v][wid] = x;
        }
    }
    __syncthreads();
    if (tid == 0) {
        const float sum_p  = red[0][0] + red[0][1] + red[0][2] + red[0][3];
        const float sum_p2 = red[1][0] + red[1][1] + red[1][2] + red[1][3];
        const float sum_t  = red[2][0] + red[2][1] + red[2][2] + red[2][3];
        const float sv5    = red[3][0] + red[3][1] + red[3][2] + red[3][3];
        const float sv10   = red[4][0] + red[4][1] + red[4][2] + red[4][3];
        const float sv20   = red[5][0] + red[5][1] + red[5][2] + red[5][3];
        const float pmean = sum_p * (1.f / 4096.f);
        const float varp  = fmaf(-sum_p * (1.f / 4096.f), sum_p, sum_p2) * (1.f / 4095.f);
        const float pstd  = __builtin_amdgcn_sqrtf(fmaxf(varp, 0.f));
        const float ipm   = __builtin_amdgcn_rcpf(pmean + 1e-8f);
        combined[row * 4 + 0] = sum_t * (1.f / 4096.f);
        combined[row * 4 + 1] = (pB - pA) * __builtin_amdgcn_rcpf(pA + 1e-8f);
        combined[row * 4 + 2] = (pB - pmean) * ipm;
        combined[row * 4 + 3] = pstd * ipm;
        const float LN2 = 0.6931471805599453f;
        volin[row * 3 + 0] = sv5  * (LN2 * 0.5f                 / 4091.f);
        volin[row * 3 + 1] = sv10 * (LN2 * (1.f / 3.f)          / 4086.f);
        volin[row * 3 + 2] = sv20 * (LN2 * 0.22941573387056174f / 4076.f);
    }
}

// -------------------------------------------------------------------------
// Kernel 2+3 FUSED (k_mc, round-10 verbatim): 8 rows/block, 256 threads,
// grid 512 = 2 blocks/CU. Proven 64 us, VGPR 112, zero spill.
// -------------------------------------------------------------------------
__global__ __launch_bounds__(256) void k_mc(const float* __restrict__ combined,
                                            const float* __restrict__ volin,
                                            const float* __restrict__ re_W,  const float* __restrict__ re_b,
                                            const float* __restrict__ re_g,  const float* __restrict__ re_be,
                                            const float* __restrict__ rh_W1, const float* __restrict__ rh_b1,
                                            const float* __restrict__ rh_W2, const float* __restrict__ rh_b2,
                                            const float* __restrict__ rv_W,  const float* __restrict__ rv_b,
                                            const float* __restrict__ rv_g,  const float* __restrict__ rv_be,
                                            const float* __restrict__ vs_W,  const float* __restrict__ vs_b,
                                            const float* __restrict__ vs_g,  const float* __restrict__ vs_be,
                                            const float* __restrict__ vc_W1, const float* __restrict__ vc_b1,
                                            const float* __restrict__ vc_W2, const float* __restrict__ vc_b2,
                                            const float* __restrict__ cn_W1,
                                            const float* __restrict__ cn_W2,
                                            const float* __restrict__ cn_b2,
                                            const float* __restrict__ cn_W3,
                                            const float* __restrict__ cn_b3,
                                            const float* __restrict__ ep,
                                            float* __restrict__ out_rf, float* __restrict__ out_rp,
                                            float* __restrict__ out_vf, float* __restrict__ out_vr,
                                            float* __restrict__ scores) {
    __shared__ __align__(16) float w2s[128 * 64];   // 32 KB  [c][j]
    __shared__ __align__(16) float epb[16][132];    // 8.4 KB
    __shared__ __align__(16) float rf_lds[8][256];  // 8 KB
    __shared__ __align__(16) float vf_lds[8][256];  // 8 KB
    __shared__ __align__(16) float psx[4][8][128];  // 16 KB (mlp uses [..][0..63])
    __shared__ __align__(16) float mvp_s[8][132];   // 4.2 KB
    __shared__ float hid_s[8][64];
    __shared__ float prt[4][8];
    __shared__ float cmb_s[8][4];
    __shared__ float vol_s[8][3];

    const int tid  = threadIdx.x;
    const int lane = tid & 63;
    const int wid  = tid >> 6;
    const int row0 = blockIdx.x * 8;

    // ---- stage W2 (8 float4/thread), ep' (2 float4/thread), row inputs ----
    #pragma unroll
    for (int k = 0; k < 8; ++k) {
        const int idx = k * 256 + tid;              // float4 index 0..2047
        *(float4*)&w2s[4 * idx] = *(const float4*)(cn_W2 + 4 * idx);
    }
    {
        const int ns = tid >> 4, c8 = (tid & 15) * 8;
        *(float4*)&epb[ns][c8]     = *(const float4*)(ep + ns * 128 + c8);
        *(float4*)&epb[ns][c8 + 4] = *(const float4*)(ep + ns * 128 + c8 + 4);
    }
    if (tid < 32) cmb_s[tid >> 2][tid & 3] = combined[(size_t)(row0 + (tid >> 2)) * 4 + (tid & 3)];
    else if (tid < 56) { int t = tid - 32; vol_s[t / 3][t % 3] = volin[(size_t)(row0 + t / 3) * 3 + t % 3]; }
    __syncthreads();

    // ================= MLP PHASES =================
    // ---- Phase A: regime expert (k=wid, o=lane) + LN over o ----
    {
        const float* w = re_W + wid * 256;
        const float w0 = w[lane], w1 = w[64 + lane], w2 = w[128 + lane], w3 = w[192 + lane];
        const float b  = re_b[wid * 64 + lane];
        const float gg = re_g[wid * 64 + lane], bb = re_be[wid * 64 + lane];
        float h[8], sm[8], sq[8];
        #pragma unroll
        for (int r = 0; r < 8; ++r) {
            float v = fmaf(cmb_s[r][0], w0, fmaf(cmb_s[r][1], w1,
                      fmaf(cmb_s[r][2], w2, fmaf(cmb_s[r][3], w3, b))));
            h[r] = fmaxf(v, 0.f);
            sm[r] = h[r]; sq[r] = h[r] * h[r];
        }
        #pragma unroll
        for (int off = 32; off > 0; off >>= 1) {
            #pragma unroll
            for (int r = 0; r < 8; ++r) {
                sm[r] += __shfl_xor(sm[r], off, 64);
                sq[r] += __shfl_xor(sq[r], off, 64);
            }
        }
        #pragma unroll
        for (int r = 0; r < 8; ++r) {
            const float mu  = sm[r] * (1.f / 64.f);
            const float var = fmaxf(sq[r] * (1.f / 64.f) - mu * mu, 0.f);
            const float y = (h[r] - mu) * rsqrtf(var + 1e-5f) * gg + bb;
            rf_lds[r][wid * 64 + lane] = y;
            out_rf[(size_t)(row0 + r) * 256 + wid * 64 + lane] = y;
        }
    }
    __syncthreads();

    // ---- Phase B: rh hidden partials, i-split across waves ----
    {
        const int i0 = wid * 64;
        float acc[8] = {0.f, 0.f, 0.f, 0.f, 0.f, 0.f, 0.f, 0.f};
        for (int i = 0; i < 64; ++i) {
            const float wv = rh_W1[(size_t)(i0 + i) * 64 + lane];
            #pragma unroll
            for (int r = 0; r < 8; ++r) acc[r] = fmaf(rf_lds[r][i0 + i], wv, acc[r]);
        }
        #pragma unroll
        for (int r = 0; r < 8; ++r) psx[wid][r][lane] = acc[r];
    }
    __syncthreads();

    for (int it = tid; it < 512; it += 256) {
        const int r = it >> 6, o = it & 63;
        const float v = psx[0][r][o] + psx[1][r][o] + psx[2][r][o] + psx[3][r][o] + rh_b1[o];
        hid_s[r][o] = fmaxf(v, 0.f);
    }
    __syncthreads();

    if (tid < 32) {
        const int r = tid >> 2, j = tid & 3;
        float acc = rh_b2[j];
        for (int i = 0; i < 64; ++i) acc = fmaf(hid_s[r][i], rh_W2[i * 4 + j], acc);
        float m = acc;
        m = fmaxf(m, __shfl_xor(m, 1, 64));
        m = fmaxf(m, __shfl_xor(m, 2, 64));
        const float e = expf(acc - m);
        float s = e;
        s += __shfl_xor(s, 1, 64);
        s += __shfl_xor(s, 2, 64);
        out_rp[(size_t)(row0 + r) * 4 + j] = e / s;
    }

    // ---- Phase E: rv + LN/128 ----
    {
        const int o = tid & 127, g = tid >> 7, wv_ = tid >> 6;
        const float w0 = rv_W[o], w1 = rv_W[128 + o], w2 = rv_W[256 + o];
        const float b = rv_b[o], gg = rv_g[o], bb = rv_be[o];
        float h[4], sm[4], sq[4];
        #pragma unroll
        for (int r4 = 0; r4 < 4; ++r4) {
            const int r = g * 4 + r4;
            float v = fmaf(vol_s[r][0], w0, fmaf(vol_s[r][1], w1, fmaf(vol_s[r][2], w2, b)));
            h[r4] = fmaxf(v, 0.f);
            sm[r4] = h[r4]; sq[r4] = h[r4] * h[r4];
        }
        #pragma unroll
        for (int off = 32; off > 0; off >>= 1) {
            #pragma unroll
            for (int r4 = 0; r4 < 4; ++r4) {
                sm[r4] += __shfl_xor(sm[r4], off, 64);
                sq[r4] += __shfl_xor(sq[r4], off, 64);
            }
        }
        if (lane == 0) {
            #pragma unroll
            for (int r4 = 0; r4 < 4; ++r4) { prt[wv_][r4 * 2] = sm[r4]; prt[wv_][r4 * 2 + 1] = sq[r4]; }
        }
        __syncthreads();
        #pragma unroll
        for (int r4 = 0; r4 < 4; ++r4) {
            const float S = prt[2 * g][2 * r4]     + prt[2 * g + 1][2 * r4];
            const float Q = prt[2 * g][2 * r4 + 1] + prt[2 * g + 1][2 * r4 + 1];
            const float mu  = S * (1.f / 128.f);
            const float var = fmaxf(Q * (1.f / 128.f) - mu * mu, 0.f);
            const float y = (h[r4] - mu) * rsqrtf(var + 1e-5f) * gg + bb;
            vf_lds[g * 4 + r4][o] = y;
            out_vf[(size_t)(row0 + g * 4 + r4) * 256 + o] = y;
        }
    }
    __syncthreads();

    // ---- Phase F: vs = LN(relu(rv @ vs_W + b)) ----
    {
        const int o = tid & 127, g = tid >> 7, wv_ = tid >> 6;
        float acc[4];
        const float b = vs_b[o];
        #pragma unroll
        for (int r4 = 0; r4 < 4; ++r4) acc[r4] = b;
        for (int i = 0; i < 128; ++i) {
            const float wv = vs_W[(size_t)i * 128 + o];
            #pragma unroll
            for (int r4 = 0; r4 < 4; ++r4) acc[r4] = fmaf(vf_lds[g * 4 + r4][i], wv, acc[r4]);
        }
        const float gg = vs_g[o], bb = vs_be[o];
        float h[4], sm[4], sq[4];
        #pragma unroll
        for (int r4 = 0; r4 < 4; ++r4) {
            h[r4] = fmaxf(acc[r4], 0.f);
            sm[r4] = h[r4]; sq[r4] = h[r4] * h[r4];
        }
        #pragma unroll
        for (int off = 32; off > 0; off >>= 1) {
            #pragma unroll
            for (int r4 = 0; r4 < 4; ++r4) {
                sm[r4] += __shfl_xor(sm[r4], off, 64);
                sq[r4] += __shfl_xor(sq[r4], off, 64);
            }
        }
        __syncthreads();
        if (lane == 0) {
            #pragma unroll
            for (int r4 = 0; r4 < 4; ++r4) { prt[wv_][r4 * 2] = sm[r4]; prt[wv_][r4 * 2 + 1] = sq[r4]; }
        }
        __syncthreads();
        #pragma unroll
        for (int r4 = 0; r4 < 4; ++r4) {
            const float S = prt[2 * g][2 * r4]     + prt[2 * g + 1][2 * r4];
            const float Q = prt[2 * g][2 * r4 + 1] + prt[2 * g + 1][2 * r4 + 1];
            const float mu  = S * (1.f / 128.f);
            const float var = fmaxf(Q * (1.f / 128.f) - mu * mu, 0.f);
            const float y = (h[r4] - mu) * rsqrtf(var + 1e-5f) * gg + bb;
            vf_lds[g * 4 + r4][128 + o] = y;
            out_vf[(size_t)(row0 + g * 4 + r4) * 256 + 128 + o] = y;
        }
    }
    __syncthreads();

    // ---- Phase G: vc hidden partials ----
    {
        const int i0 = wid * 64;
        float acc[8] = {0.f, 0.f, 0.f, 0.f, 0.f, 0.f, 0.f, 0.f};
        for (int i = 0; i < 64; ++i) {
            const float wv = vc_W1[(size_t)(i0 + i) * 64 + lane];
            #pragma unroll
            for (int r = 0; r < 8; ++r) acc[r] = fmaf(vf_lds[r][i0 + i], wv, acc[r]);
        }
        #pragma unroll
        for (int r = 0; r < 8; ++r) psx[wid][r][lane] = acc[r];
    }
    __syncthreads();

    for (int it = tid; it < 512; it += 256) {
        const int r = it >> 6, o = it & 63;
        const float v = psx[0][r][o] + psx[1][r][o] + psx[2][r][o] + psx[3][r][o] + vc_b1[o];
        hid_s[r][o] = fmaxf(v, 0.f);
    }
    __syncthreads();
    if (tid < 32) {
        const int r = tid >> 2, j = tid & 3;
        float acc = vc_b2[j];
        for (int i = 0; i < 64; ++i) acc = fmaf(hid_s[r][i], vc_W2[i * 4 + j], acc);
        float m = acc;
        m = fmaxf(m, __shfl_xor(m, 1, 64));
        m = fmaxf(m, __shfl_xor(m, 2, 64));
        const float e = expf(acc - m);
        float s = e;
        s += __shfl_xor(s, 1, 64);
        s += __shfl_xor(s, 2, 64);
        out_vr[(size_t)(row0 + r) * 4 + j] = e / s;
    }
    __syncthreads();   // psx free; rf/vf final

    // ================= CROSS PHASES =================
    // ---- phase A: mvp[r][o] = [rf|vf][r] . W1[:,o]; wave wid covers
    // i in [128*wid, 128*wid+128); lane = 32p + q (p = i parity, o = 4q..4q+3)
    {
        const int p = lane >> 5;
        const int q = lane & 31;
        const float* mbase = (wid < 2) ? &rf_lds[0][0] + wid * 128
                                       : &vf_lds[0][0] + (wid - 2) * 128;
        float acc[8][4] = {{0.f}};
        #pragma unroll 8
        for (int s = 0; s < 64; ++s) {
            const int i = 2 * s + p;
            const float4 w1v = *(const float4*)(cn_W1 + (size_t)(wid * 128 + i) * 128 + 4 * q);
            #pragma unroll
            for (int r = 0; r < 8; ++r) {
                const float m = mbase[r * 256 + i];
                acc[r][0] = fmaf(m, w1v.x, acc[r][0]);
                acc[r][1] = fmaf(m, w1v.y, acc[r][1]);
                acc[r][2] = fmaf(m, w1v.z, acc[r][2]);
                acc[r][3] = fmaf(m, w1v.w, acc[r][3]);
            }
        }
        #pragma unroll
        for (int r = 0; r < 8; ++r) {
            #pragma unroll
            for (int k = 0; k < 4; ++k) acc[r][k] += __shfl_xor(acc[r][k], 32, 64);
        }
        if (p == 0) {
            #pragma unroll
            for (int r = 0; r < 8; ++r)
                *(float4*)&psx[wid][r][4 * q] =
                    make_float4(acc[r][0], acc[r][1], acc[r][2], acc[r][3]);
        }
    }
    __syncthreads();

    // combine 4 wave-partials -> mvp_s[8][128]
    #pragma unroll
    for (int k = 0; k < 4; ++k) {
        const int idx = k * 256 + tid;
        const int r = idx >> 7, c = idx & 127;
        mvp_s[r][c] = psx[0][r][c] + psx[1][r][c] + psx[2][r][c] + psx[3][r][c];
    }
    __syncthreads();

    // ---- phase B: thread = (ns = tid>>4, t = tid&15), j = 4t..4t+3, 8 rows ----
    {
        const int ns = tid >> 4;
        const int t  = tid & 15;
        float acc[8][4];
        #pragma unroll
        for (int r = 0; r < 8; ++r)
            #pragma unroll
            for (int k = 0; k < 4; ++k) acc[r][k] = 0.f;

        #pragma unroll 2
        for (int c = 0; c < 128; c += 4) {
            float4 m4[8];
            #pragma unroll
            for (int r = 0; r < 8; ++r) m4[r] = *(const float4*)&mvp_s[r][c];
            const float4 e4 = *(const float4*)&epb[ns][c];
            {   const float4 w2v = *(const float4*)&w2s[(c + 0) * 64 + 4 * t];
                #pragma unroll
                for (int r = 0; r < 8; ++r) {
                    const float h = fmaxf(m4[r].x + e4.x, 0.f);
                    acc[r][0] = fmaf(h, w2v.x, acc[r][0]); acc[r][1] = fmaf(h, w2v.y, acc[r][1]);
                    acc[r][2] = fmaf(h, w2v.z, acc[r][2]); acc[r][3] = fmaf(h, w2v.w, acc[r][3]); } }
            {   const float4 w2v = *(const float4*)&w2s[(c + 1) * 64 + 4 * t];
                #pragma unroll
                for (int r = 0; r < 8; ++r) {
                    const float h = fmaxf(m4[r].y + e4.y, 0.f);
                    acc[r][0] = fmaf(h, w2v.x, acc[r][0]); acc[r][1] = fmaf(h, w2v.y, acc[r][1]);
                    acc[r][2] = fmaf(h, w2v.z, acc[r][2]); acc[r][3] = fmaf(h, w2v.w, acc[r][3]); } }
            {   const float4 w2v = *(const float4*)&w2s[(c + 2) * 64 + 4 * t];
                #pragma unroll
                for (int r = 0; r < 8; ++r) {
                    const float h = fmaxf(m4[r].z + e4.z, 0.f);
                    acc[r][0] = fmaf(h, w2v.x, acc[r][0]); acc[r][1] = fmaf(h, w2v.y, acc[r][1]);
                    acc[r][2] = fmaf(h, w2v.z, acc[r][2]); acc[r][3] = fmaf(h, w2v.w, acc[r][3]); } }
            {   const float4 w2v = *(const float4*)&w2s[(c + 3) * 64 + 4 * t];
                #pragma unroll
                for (int r = 0; r < 8; ++r) {
                    const float h = fmaxf(m4[r].w + e4.w, 0.f);
                    acc[r][0] = fmaf(h, w2v.x, acc[r][0]); acc[r][1] = fmaf(h, w2v.y, acc[r][1]);
                    acc[r][2] = fmaf(h, w2v.z, acc[r][2]); acc[r][3] = fmaf(h, w2v.w, acc[r][3]); } }
        }

        const float4 b2v = *(const float4*)(cn_b2 + 4 * t);
        const float4 w3v = *(const float4*)(cn_W3 + 4 * t);
        const float  b3v = cn_b3[0];
        #pragma unroll
        for (int r = 0; r < 8; ++r) {
            float s =      fmaxf(acc[r][0] + b2v.x, 0.f) * w3v.x;
            s = fmaf(fmaxf(acc[r][1] + b2v.y, 0.f), w3v.y, s);
            s = fmaf(fmaxf(acc[r][2] + b2v.z, 0.f), w3v.z, s);
            s = fmaf(fmaxf(acc[r][3] + b2v.w, 0.f), w3v.w, s);
            s += __shfl_xor(s, 1, 64);
            s += __shfl_xor(s, 2, 64);
            s += __shfl_xor(s, 4, 64);
            s += __shfl_xor(s, 8, 64);
            if (t == 0) scores[(size_t)(row0 + r) * 16 + ns] = s + b3v;
        }
    }
}

// -------------------------------------------------------------------------
extern "C" void kernel_launch(void* const* d_in, const int* in_sizes, int n_in,
                              void* d_out, int out_size, void* d_ws, size_t ws_size,
                              hipStream_t stream) {
    (void)in_sizes; (void)n_in; (void)out_size; (void)ws_size;

    const float* price = (const float*)d_in[0];
    const float* re_W  = (const float*)d_in[1];
    const float* re_b  = (const float*)d_in[2];
    const float* re_g  = (const float*)d_in[3];
    const float* re_be = (const float*)d_in[4];
    const float* rh_W1 = (const float*)d_in[5];
    const float* rh_b1 = (const float*)d_in[6];
    const float* rh_W2 = (const float*)d_in[7];
    const float* rh_b2 = (const float*)d_in[8];
    const float* rv_W  = (const float*)d_in[9];
    const float* rv_b  = (const float*)d_in[10];
    const float* rv_g  = (const float*)d_in[11];
    const float* rv_be = (const float*)d_in[12];
    const float* vs_W  = (const float*)d_in[13];
    const float* vs_b  = (const float*)d_in[14];
    const float* vs_g  = (const float*)d_in[15];
    const float* vs_be = (const float*)d_in[16];
    const float* vc_W1 = (const float*)d_in[17];
    const float* vc_b1 = (const float*)d_in[18];
    const float* vc_W2 = (const float*)d_in[19];
    const float* vc_b2 = (const float*)d_in[20];
    const float* emb   = (const float*)d_in[21];
    const float* cn_W1 = (const float*)d_in[22];
    const float* cn_b1 = (const float*)d_in[23];
    const float* cn_W2 = (const float*)d_in[24];
    const float* cn_b2 = (const float*)d_in[25];
    const float* cn_W3 = (const float*)d_in[26];
    const float* cn_b3 = (const float*)d_in[27];

    float* out    = (float*)d_out;
    float* out_rf = out;                       // 4096*256
    float* out_rp = out_rf + 4096 * 256;       // 4096*4
    float* out_vf = out_rp + 4096 * 4;         // 4096*256
    float* out_vr = out_vf + 4096 * 256;       // 4096*4
    float* out_sc = out_vr + 4096 * 4;         // 4096*16

    float* ws       = (float*)d_ws;
    float* combined = ws;                      // 4096*4
    float* volin    = combined + 4096 * 4;     // 4096*3
    float* ep       = volin + 4096 * 3;        // 16*128

    hipLaunchKernelGGL(k_ep,    dim3(8),    dim3(256), 0, stream, emb, cn_W1, cn_b1, ep);
    hipLaunchKernelGGL(k_stats, dim3(4096), dim3(256), 0, stream, price, combined, volin);
    hipLaunchKernelGGL(k_mc,    dim3(512),  dim3(256), 0, stream, combined, volin,
                       re_W, re_b, re_g, re_be, rh_W1, rh_b1, rh_W2, rh_b2,
                       rv_W, rv_b, rv_g, rv_be, vs_W, vs_b, vs_g, vs_be,
                       vc_W1, vc_b1, vc_W2, vc_b2,
                       cn_W1, cn_W2, cn_b2, cn_W3, cn_b3, ep,
                       out_rf, out_rp, out_vf, out_vr, out_sc);
}